// Round 1
// 1502.497 us; speedup vs baseline: 1.0090x; 1.0090x over previous
//
#include <hip/hip_runtime.h>

typedef unsigned int uint;
typedef unsigned short ushort;
typedef short short8 __attribute__((ext_vector_type(8)));
typedef float floatx4 __attribute__((ext_vector_type(4)));
typedef ushort ushortx8 __attribute__((ext_vector_type(8)));
typedef ushort ushortx4 __attribute__((ext_vector_type(4)));
typedef uint uintx4 __attribute__((ext_vector_type(4)));

#define DEV static __device__ __forceinline__

#define Bsz 16
#define Cch 512
#define Tt 128
#define Nn 64
#define Hh 8
#define HD 64
#define Pp 8192        /* T*N */
#define BPOS 131072    /* B*P  */
#define C3 1536

// chunk swizzle: tiles stored as 16-byte chunks (8 bf16); row has 8 chunks
DEV int swz(int row, int c8) { return row * 8 + (c8 ^ (row & 7) ^ ((row >> 3) & 7)); }

DEV ushort f2bf(float f) {
  uint u = __float_as_uint(f);
  return (ushort)((u + 0x7FFFu + ((u >> 16) & 1u)) >> 16);  // RNE
}
DEV float bf2f(ushort h) { return __uint_as_float(((uint)h) << 16); }

// async global->LDS, 16B per lane. dst must be wave-uniform base; HW writes
// lane L at dst + L*16. Source address is per-lane (carries the inverse swizzle).
DEV void gll16(const ushort* src, ushort* dst) {
  __builtin_amdgcn_global_load_lds(
      (const __attribute__((address_space(1))) unsigned int*)src,
      (__attribute__((address_space(3))) unsigned int*)dst, 16, 0, 0);
}

// ---------------------------------------------------------------------------
// elementwise fp32 -> bf16 (weights)
// ---------------------------------------------------------------------------
__global__ __launch_bounds__(256) void k_cvt(const float* __restrict__ src,
                                             ushort* __restrict__ dst, int n) {
  int gid = blockIdx.x * 256 + threadIdx.x;
  int i8 = gid * 8;
  if (i8 < n) {
    floatx4 a = *(const floatx4*)&src[i8];
    floatx4 b = *(const floatx4*)&src[i8 + 4];
    ushortx8 o;
#pragma unroll
    for (int j = 0; j < 4; ++j) { o[j] = f2bf(a[j]); o[j + 4] = f2bf(b[j]); }
    *(ushortx8*)&dst[i8] = o;
  }
}

// ---------------------------------------------------------------------------
// x fp32 [b][c][p] -> xT bf16 [b][p][c]  (64x64 tiles via swizzled LDS)
// ---------------------------------------------------------------------------
__global__ __launch_bounds__(256) void k_transpose_x(const float* __restrict__ x,
                                                     ushort* __restrict__ xT) {
  int p0 = blockIdx.x * 64, c0 = blockIdx.y * 64, b = blockIdx.z;
  __shared__ __align__(16) ushort sm[4096];
  int tid = threadIdx.x;
  const float* xb = x + (size_t)b * Cch * Pp;
  ushort* xTb = xT + (size_t)b * Pp * Cch;
#pragma unroll
  for (int it = 0; it < 4; ++it) {
    int cc = tid + it * 256;
    int r = cc >> 4, c4 = cc & 15;
    floatx4 v = *(const floatx4*)&xb[(size_t)(c0 + r) * Pp + p0 + c4 * 4];
    ushortx4 o;
#pragma unroll
    for (int j = 0; j < 4; ++j) o[j] = f2bf(v[j]);
    *(ushortx4*)&sm[swz(r, c4 >> 1) * 8 + (c4 & 1) * 4] = o;
  }
  __syncthreads();
#pragma unroll
  for (int it = 0; it < 2; ++it) {
    int cc = tid + it * 256;
    int pl = cc >> 3, c8 = cc & 7;
    ushortx8 o;
#pragma unroll
    for (int j = 0; j < 8; ++j) {
      int c = c8 * 8 + j;
      o[j] = sm[swz(c, pl >> 3) * 8 + (pl & 7)];
    }
    *(ushortx8*)&xTb[(size_t)(p0 + pl) * Cch + c0 + c8 * 8] = o;
  }
}

// ---------------------------------------------------------------------------
// D_bf16[m][n] = sum_k A[m][k]*W[n][k] + bias[n]  (A,W bf16; bias fp32)
// 128x128 block tile, BK=64, 4 waves each 64x64; global_load_lds staging with
// pre-swizzled source (swizzle is an XOR involution; LDS dest stays linear)
// ---------------------------------------------------------------------------
__global__ __launch_bounds__(256) void k_gemm_bt(const ushort* __restrict__ A,
                                                 const ushort* __restrict__ W,
                                                 const float* __restrict__ bias,
                                                 ushort* __restrict__ D,
                                                 int K, int ldD,
                                                 size_t sAb, size_t sDb) {
  __shared__ __align__(16) ushort sm[16384];
  ushort* sA = sm;
  ushort* sB = sm + 8192;
  int tid = threadIdx.x;
  int lane = tid & 63, w = tid >> 6;
  int wm = (w & 1) * 64, wn = (w >> 1) * 64;
  size_t m0 = (size_t)blockIdx.y * 128;
  size_t n0 = (size_t)blockIdx.x * 128;
  const ushort* Ab = A + (size_t)blockIdx.z * sAb;
  ushort* Db = D + (size_t)blockIdx.z * sDb;

  floatx4 zero4 = {0.f, 0.f, 0.f, 0.f};
  floatx4 acc[4][4];
#pragma unroll
  for (int i = 0; i < 4; ++i)
#pragma unroll
    for (int j = 0; j < 4; ++j) acc[i][j] = zero4;

  for (int kb = 0; kb < K; kb += 64) {
    __syncthreads();  // prior compute done reading sA/sB
#pragma unroll
    for (int it = 0; it < 4; ++it) {
      int i = it * 256 + tid;  // chunk index 0..1023
      int r = i >> 3;
      int c8 = (i & 7) ^ (r & 7) ^ ((r >> 3) & 7);  // inverse (=same) swizzle
      gll16(&Ab[(m0 + r) * (size_t)K + kb + c8 * 8], &sA[(size_t)(it * 256 + w * 64) * 8]);
      gll16(&W[(n0 + r) * (size_t)K + kb + c8 * 8], &sB[(size_t)(it * 256 + w * 64) * 8]);
    }
    __syncthreads();  // drains vmcnt for global_load_lds
#pragma unroll
    for (int kk = 0; kk < 2; ++kk) {
      int g = kk * 4 + (lane >> 4);
      int rr = lane & 15;
      short8 af[4], bf[4];
#pragma unroll
      for (int i = 0; i < 4; ++i) af[i] = *(const short8*)&sA[swz(wm + i * 16 + rr, g) * 8];
#pragma unroll
      for (int j = 0; j < 4; ++j) bf[j] = *(const short8*)&sB[swz(wn + j * 16 + rr, g) * 8];
#pragma unroll
      for (int i = 0; i < 4; ++i)
#pragma unroll
        for (int j = 0; j < 4; ++j)
          acc[i][j] = __builtin_amdgcn_mfma_f32_16x16x32_bf16(af[i], bf[j], acc[i][j], 0, 0, 0);
    }
  }

  __syncthreads();
  int quad = lane >> 4, col = lane & 15;
#pragma unroll
  for (int j = 0; j < 4; ++j) {
    int n_loc = wn + j * 16 + col;
    float bj = bias[n0 + n_loc];
#pragma unroll
    for (int i = 0; i < 4; ++i)
#pragma unroll
      for (int r = 0; r < 4; ++r) {
        int m_loc = wm + i * 16 + quad * 4 + r;
        sm[(m_loc * 16 + ((n_loc >> 3) ^ (m_loc & 7) ^ ((m_loc >> 3) & 7))) * 8 + (n_loc & 7)] =
            f2bf(acc[i][j][r] + bj);
      }
  }
  __syncthreads();
#pragma unroll
  for (int it = 0; it < 8; ++it) {
    int cc = tid + it * 256;
    int m_loc = cc >> 4, cn = cc & 15;
    uintx4 v = *(const uintx4*)&sm[(m_loc * 16 + (cn ^ (m_loc & 7) ^ ((m_loc >> 3) & 7))) * 8];
    *(uintx4*)&Db[(m0 + m_loc) * (size_t)ldD + n0 + cn * 8] = v;
  }
}

// ---------------------------------------------------------------------------
// GEMM2: D_fp32[n][m] = sum_k A[m][k]*W[n][k] + bias[n]   (transposed fp32 out)
// + fused BN partial statistics (per-channel sum / sumsq via atomics)
// ---------------------------------------------------------------------------
__global__ __launch_bounds__(256) void k_gemm2_t(const ushort* __restrict__ A,
                                                 const ushort* __restrict__ W,
                                                 const float* __restrict__ bias,
                                                 float* __restrict__ D,
                                                 int K, int ldD,
                                                 size_t sAb, size_t sDb,
                                                 float* __restrict__ sums,
                                                 float* __restrict__ sqs) {
  __shared__ __align__(16) ushort sm[16384];
  ushort* sA = sm;
  ushort* sB = sm + 8192;
  float* smf = (float*)sm;
  int tid = threadIdx.x;
  int lane = tid & 63, w = tid >> 6;
  int wm = (w & 1) * 64, wn = (w >> 1) * 64;
  size_t m0 = (size_t)blockIdx.y * 128;
  size_t n0 = (size_t)blockIdx.x * 128;
  const ushort* Ab = A + (size_t)blockIdx.z * sAb;
  float* Db = D + (size_t)blockIdx.z * sDb;

  floatx4 zero4 = {0.f, 0.f, 0.f, 0.f};
  floatx4 acc[4][4];
#pragma unroll
  for (int i = 0; i < 4; ++i)
#pragma unroll
    for (int j = 0; j < 4; ++j) acc[i][j] = zero4;

  for (int kb = 0; kb < K; kb += 64) {
    __syncthreads();
#pragma unroll
    for (int it = 0; it < 4; ++it) {
      int i = it * 256 + tid;
      int r = i >> 3;
      int c8 = (i & 7) ^ (r & 7) ^ ((r >> 3) & 7);
      gll16(&Ab[(m0 + r) * (size_t)K + kb + c8 * 8], &sA[(size_t)(it * 256 + w * 64) * 8]);
      gll16(&W[(n0 + r) * (size_t)K + kb + c8 * 8], &sB[(size_t)(it * 256 + w * 64) * 8]);
    }
    __syncthreads();
#pragma unroll
    for (int kk = 0; kk < 2; ++kk) {
      int g = kk * 4 + (lane >> 4);
      int rr = lane & 15;
      short8 af[4], bf[4];
#pragma unroll
      for (int i = 0; i < 4; ++i) af[i] = *(const short8*)&sA[swz(wm + i * 16 + rr, g) * 8];
#pragma unroll
      for (int j = 0; j < 4; ++j) bf[j] = *(const short8*)&sB[swz(wn + j * 16 + rr, g) * 8];
#pragma unroll
      for (int i = 0; i < 4; ++i)
#pragma unroll
        for (int j = 0; j < 4; ++j)
          acc[i][j] = __builtin_amdgcn_mfma_f32_16x16x32_bf16(af[i], bf[j], acc[i][j], 0, 0, 0);
    }
  }

  int quad = lane >> 4, col = lane & 15;
#pragma unroll
  for (int h = 0; h < 2; ++h) {
    __syncthreads();
    if ((w >> 1) == h) {  // waves whose wn == h*64 own this half
#pragma unroll
      for (int j = 0; j < 4; ++j) {
        int n1 = j * 16 + col;  // row within half
        float bj = bias[n0 + h * 64 + n1];
#pragma unroll
        for (int i = 0; i < 4; ++i) {
          int mb = wm + i * 16 + quad * 4;
          floatx4 v4;
#pragma unroll
          for (int r = 0; r < 4; ++r) v4[r] = acc[i][j][r] + bj;
          *(floatx4*)&smf[n1 * 128 + (mb ^ ((n1 & 7) << 2))] = v4;
        }
      }
    }
    __syncthreads();
#pragma unroll
    for (int it = 0; it < 8; ++it) {
      int cc = tid + it * 256;
      int n2 = cc >> 5, ck = cc & 31;
      floatx4 v = *(const floatx4*)&smf[n2 * 128 + ((ck * 4) ^ ((n2 & 7) << 2))];
      *(floatx4*)&Db[(n0 + h * 64 + n2) * (size_t)ldD + m0 + ck * 4] = v;
      // fused BN stats: 32 threads (same n2) reduce 128 m-values
      float s = v[0] + v[1] + v[2] + v[3];
      float q = v[0] * v[0] + v[1] * v[1] + v[2] * v[2] + v[3] * v[3];
#pragma unroll
      for (int off = 16; off > 0; off >>= 1) {
        s += __shfl_down(s, off, 32);
        q += __shfl_down(q, off, 32);
      }
      if ((tid & 31) == 0) {
        atomicAdd(&sums[n0 + h * 64 + n2], s);
        atomicAdd(&sqs[n0 + h * 64 + n2], q);
      }
    }
  }
}

// ---------------------------------------------------------------------------
// attention: block per (h,t), blockIdx.y = batch within group
// qkv bf16 [p][1536]; aT bf16 [p][512]
// ---------------------------------------------------------------------------
__global__ __launch_bounds__(256) void k_attn(const ushort* __restrict__ qkv,
                                              ushort* __restrict__ aT,
                                              size_t sQb, size_t sAb) {
  int bx = blockIdx.x;
  int t = bx & 127, h = bx >> 7;
  __shared__ __align__(16) ushort sm[16384];
  ushort* qs = sm;
  ushort* ks = sm + 4096;
  ushort* vt = sm + 8192;
  ushort* ss = sm + 12288;
  int tid = threadIdx.x, lane = tid & 63, w = tid >> 6;
  int quad = lane >> 4, col = lane & 15;
  const ushort* base = qkv + (size_t)blockIdx.y * sQb + (size_t)(t * 64) * C3 + h * 64;

#pragma unroll
  for (int it = 0; it < 2; ++it) {
    int i = it * 256 + tid;  // chunk 0..511
    int r = i >> 3;
    int c8 = (i & 7) ^ (r & 7) ^ ((r >> 3) & 7);
    gll16(&base[(size_t)r * C3 + c8 * 8], &qs[(size_t)(it * 256 + w * 64) * 8]);
    gll16(&base[(size_t)r * C3 + 512 + c8 * 8], &ks[(size_t)(it * 256 + w * 64) * 8]);
    int n = i >> 3, d8 = i & 7;
    ushortx8 vv = *(const ushortx8*)&base[(size_t)n * C3 + 1024 + d8 * 8];
#pragma unroll
    for (int j = 0; j < 8; ++j) {
      int dp = d8 * 8 + j;
      vt[swz(dp, n >> 3) * 8 + (n & 7)] = vv[j];  // vT[d][m]
    }
  }
  __syncthreads();

  floatx4 zero4 = {0.f, 0.f, 0.f, 0.f};
  floatx4 accs[4] = {zero4, zero4, zero4, zero4};
#pragma unroll
  for (int kk = 0; kk < 2; ++kk) {
    int g = kk * 4 + quad;
    short8 aq = *(const short8*)&qs[swz(w * 16 + col, g) * 8];
#pragma unroll
    for (int j = 0; j < 4; ++j) {
      short8 bk = *(const short8*)&ks[swz(j * 16 + col, g) * 8];
      accs[j] = __builtin_amdgcn_mfma_f32_16x16x32_bf16(aq, bk, accs[j], 0, 0, 0);
    }
  }
#pragma unroll
  for (int j = 0; j < 4; ++j)
#pragma unroll
    for (int r = 0; r < 4; ++r) {
      int n = w * 16 + quad * 4 + r, m = j * 16 + col;
      ss[swz(n, m >> 3) * 8 + (m & 7)] = f2bf(accs[j][r] * 0.125f);
    }
  __syncthreads();

  floatx4 acco[4] = {zero4, zero4, zero4, zero4};
#pragma unroll
  for (int kk = 0; kk < 2; ++kk) {
    int g = kk * 4 + quad;
    short8 as = *(const short8*)&ss[swz(w * 16 + col, g) * 8];
#pragma unroll
    for (int j = 0; j < 4; ++j) {
      short8 bv = *(const short8*)&vt[swz(j * 16 + col, g) * 8];
      acco[j] = __builtin_amdgcn_mfma_f32_16x16x32_bf16(as, bv, acco[j], 0, 0, 0);
    }
  }
#pragma unroll
  for (int j = 0; j < 4; ++j)
#pragma unroll
    for (int r = 0; r < 4; ++r) {
      int n = w * 16 + quad * 4 + r, dp = j * 16 + col;
      qs[swz(n, dp >> 3) * 8 + (dp & 7)] = f2bf(acco[j][r]);  // qs dead, reuse
    }
  __syncthreads();
  ushort* aTb = aT + (size_t)blockIdx.y * sAb + (size_t)(t * 64) * Cch + h * 64;
#pragma unroll
  for (int it = 0; it < 2; ++it) {
    int cc = tid + it * 256;
    int n = cc >> 3, c8 = cc & 7;
    uintx4 v = *(const uintx4*)&qs[swz(n, c8) * 8];
    *(uintx4*)&aTb[(size_t)n * Cch + c8 * 8] = v;
  }
}

// ---------------------------------------------------------------------------
// BN finalize + in-place BN+residual
// ---------------------------------------------------------------------------
__global__ __launch_bounds__(256) void k_zero(float* p, int n) {
  int i = blockIdx.x * 256 + threadIdx.x;
  if (i < n) p[i] = 0.f;
}

__global__ __launch_bounds__(256) void k_bnfin(const float* __restrict__ sums,
                                               const float* __restrict__ sqs,
                                               const float* __restrict__ gamma,
                                               const float* __restrict__ beta,
                                               float* __restrict__ scaleS,
                                               float* __restrict__ shiftS) {
  int c = threadIdx.x + blockIdx.x * 256;
  if (c < Cch) {
    float inv = 1.0f / (float)BPOS;
    float mean = sums[c] * inv;
    float var = sqs[c] * inv - mean * mean;
    float sc = gamma[c] * rsqrtf(var + 1e-5f);
    scaleS[c] = sc;
    shiftS[c] = beta[c] - mean * sc;
  }
}

// y (= d_out fp32, channel-major) in place: y = y*scale[c] + shift[c] + x
__global__ __launch_bounds__(256) void k_final(const float* __restrict__ x,
                                               float* __restrict__ y,
                                               const float* __restrict__ scaleS,
                                               const float* __restrict__ shiftS) {
  size_t gid = (size_t)blockIdx.x * 256 + threadIdx.x;
  size_t i4 = gid * 4;
  int c = (int)((i4 >> 13) & 511);
  float sc = scaleS[c], sh = shiftS[c];
  floatx4 yv = *(floatx4*)&y[i4];
  floatx4 xv = *(const floatx4*)&x[i4];
  floatx4 o;
#pragma unroll
  for (int j = 0; j < 4; ++j) o[j] = yv[j] * sc + sh + xv[j];
  *(floatx4*)&y[i4] = o;
}

// ---------------------------------------------------------------------------
extern "C" void kernel_launch(void* const* d_in, const int* in_sizes, int n_in,
                              void* d_out, int out_size, void* d_ws, size_t ws_size,
                              hipStream_t stream) {
  const float* x      = (const float*)d_in[0];
  const float* w_qkv  = (const float*)d_in[1];
  const float* b_qkv  = (const float*)d_in[2];
  const float* w_proj = (const float*)d_in[3];
  const float* b_proj = (const float*)d_in[4];
  const float* gamma  = (const float*)d_in[5];
  const float* beta   = (const float*)d_in[6];
  float* outf = (float*)d_out;  // 268,435,456 B

  // ws (~36 MB): qkv_ws (batch 15) | aT_ws (batch 15) | wqkvb | wprojb | stats
  char* ws = (char*)d_ws;
  ushort* qkv_ws = (ushort*)ws;                         // 25,165,824 B
  ushort* aT_ws  = (ushort*)(ws + 25165824ull);         //  8,388,608 B
  ushort* wqkvb  = (ushort*)(ws + 33554432ull);         //  1,572,864 B
  ushort* wprojb = (ushort*)(ws + 35127296ull);         //    524,288 B
  float*  st     = (float*)(ws + 35651584ull);          //      8 KB
  float* sums = st, *sqs = st + 512, *scaleS = st + 1024, *shiftS = st + 1536;

  // d_out aliasing plan (byte-exact, verified offsets):
  //  - xT bf16 [16][8192][512] lives in the UPPER half [134217728, 268435456).
  //    Slab b: [134217728 + b*8388608, +8388608). Dead after gemm1(b).
  //  - attn writes aT_b OVER its own xT slab (gemm1(b) already consumed it).
  //  - qkv for 5 batches at a time staged in the LOWER half [0, 125829120)
  //    (y not written until all gemm1/attn done).
  //  - gemm2 groups {0-7},{8-11},{12-13},{14}: y-slab stride (16777216 B) is
  //    2x aT stride, so each group's y-writes cover only ALREADY-CONSUMED aT
  //    slabs; boundaries are exact (e.g. y[8..11] ends at 201326592 = aT8
  //    start). Batch 15 would self-overlap (y15 [251658240,268435456) covers
  //    aT15 [260046848,...)), so batch 15 routes through ws (qkv_ws/aT_ws).
  ushort* xT   = (ushort*)((char*)d_out + 134217728ull);
  ushort* qkvL = (ushort*)d_out;

  const size_t PC = (size_t)Pp * Cch;  // xT / aT batch stride (elements)
  const size_t PQ = (size_t)Pp * C3;   // qkv batch stride (elements)
  const size_t CP = (size_t)Cch * Pp;  // y batch stride (floats)

  k_zero<<<dim3(8), 256, 0, stream>>>(st, 2048);
  k_cvt<<<dim3(384), 256, 0, stream>>>(w_qkv, wqkvb, 3 * Cch * Cch);
  k_cvt<<<dim3(128), 256, 0, stream>>>(w_proj, wprojb, Cch * Cch);
  k_transpose_x<<<dim3(Pp / 64, Cch / 64, Bsz), 256, 0, stream>>>(x, xT);

  // batches 0..14 in groups of 5 (qkv staged in d_out lower half)
  for (int g = 0; g < 3; ++g) {
    int b0 = g * 5;
    k_gemm_bt<<<dim3(C3 / 128, Pp / 128, 5), 256, 0, stream>>>(
        xT + (size_t)b0 * PC, wqkvb, b_qkv, qkvL, Cch, C3, PC, PQ);
    k_attn<<<dim3(Hh * Tt, 5), 256, 0, stream>>>(qkvL, xT + (size_t)b0 * PC, PQ, PC);
  }
  // batch 15 through ws buffers
  k_gemm_bt<<<dim3(C3 / 128, Pp / 128, 1), 256, 0, stream>>>(
      xT + 15 * PC, wqkvb, b_qkv, qkv_ws, Cch, C3, 0, 0);
  k_attn<<<dim3(Hh * Tt, 1), 256, 0, stream>>>(qkv_ws, aT_ws, 0, 0);

  // gemm2 groups (fused BN stats)
  k_gemm2_t<<<dim3(Cch / 128, Pp / 128, 8), 256, 0, stream>>>(
      xT + 0 * PC, wprojb, b_proj, outf + 0 * CP, Cch, Pp, PC, CP, sums, sqs);
  k_gemm2_t<<<dim3(Cch / 128, Pp / 128, 4), 256, 0, stream>>>(
      xT + 8 * PC, wprojb, b_proj, outf + 8 * CP, Cch, Pp, PC, CP, sums, sqs);
  k_gemm2_t<<<dim3(Cch / 128, Pp / 128, 2), 256, 0, stream>>>(
      xT + 12 * PC, wprojb, b_proj, outf + 12 * CP, Cch, Pp, PC, CP, sums, sqs);
  k_gemm2_t<<<dim3(Cch / 128, Pp / 128, 1), 256, 0, stream>>>(
      xT + 14 * PC, wprojb, b_proj, outf + 14 * CP, Cch, Pp, 0, 0, sums, sqs);
  k_gemm2_t<<<dim3(Cch / 128, Pp / 128, 1), 256, 0, stream>>>(
      aT_ws, wprojb, b_proj, outf + 15 * CP, Cch, Pp, 0, 0, sums, sqs);

  k_bnfin<<<dim3(2), 256, 0, stream>>>(sums, sqs, gamma, beta, scaleS, shiftS);
  k_final<<<dim3(BPOS * Cch / 4 / 256), 256, 0, stream>>>(x, outf, scaleS, shiftS);
}

// Round 2
// 1201.330 us; speedup vs baseline: 1.2620x; 1.2507x over previous
//
#include <hip/hip_runtime.h>

typedef unsigned int uint;
typedef unsigned short ushort;
typedef short short8 __attribute__((ext_vector_type(8)));
typedef float floatx4 __attribute__((ext_vector_type(4)));
typedef ushort ushortx8 __attribute__((ext_vector_type(8)));
typedef ushort ushortx4 __attribute__((ext_vector_type(4)));
typedef uint uintx4 __attribute__((ext_vector_type(4)));

#define DEV static __device__ __forceinline__

#define Bsz 16
#define Cch 512
#define Tt 128
#define Nn 64
#define Hh 8
#define HD 64
#define Pp 8192        /* T*N */
#define BPOS 131072    /* B*P  */
#define C3 1536

// chunk swizzle: tiles stored as 16-byte chunks (8 bf16); row has 8 chunks
DEV int swz(int row, int c8) { return row * 8 + (c8 ^ (row & 7) ^ ((row >> 3) & 7)); }

DEV ushort f2bf(float f) {
  uint u = __float_as_uint(f);
  return (ushort)((u + 0x7FFFu + ((u >> 16) & 1u)) >> 16);  // RNE
}
DEV float bf2f(ushort h) { return __uint_as_float(((uint)h) << 16); }

// async global->LDS, 16B per lane. dst must be wave-uniform base; HW writes
// lane L at dst + L*16. Source address is per-lane (carries the inverse swizzle).
DEV void gll16(const ushort* src, ushort* dst) {
  __builtin_amdgcn_global_load_lds(
      (const __attribute__((address_space(1))) unsigned int*)src,
      (__attribute__((address_space(3))) unsigned int*)dst, 16, 0, 0);
}

// ---------------------------------------------------------------------------
// elementwise fp32 -> bf16 (weights)
// ---------------------------------------------------------------------------
__global__ __launch_bounds__(256) void k_cvt(const float* __restrict__ src,
                                             ushort* __restrict__ dst, int n) {
  int gid = blockIdx.x * 256 + threadIdx.x;
  int i8 = gid * 8;
  if (i8 < n) {
    floatx4 a = *(const floatx4*)&src[i8];
    floatx4 b = *(const floatx4*)&src[i8 + 4];
    ushortx8 o;
#pragma unroll
    for (int j = 0; j < 4; ++j) { o[j] = f2bf(a[j]); o[j + 4] = f2bf(b[j]); }
    *(ushortx8*)&dst[i8] = o;
  }
}

// ---------------------------------------------------------------------------
// x fp32 [b][c][p] -> xT bf16 [b][p][c]  (64x64 tiles via swizzled LDS)
// ---------------------------------------------------------------------------
__global__ __launch_bounds__(256) void k_transpose_x(const float* __restrict__ x,
                                                     ushort* __restrict__ xT) {
  int p0 = blockIdx.x * 64, c0 = blockIdx.y * 64, b = blockIdx.z;
  __shared__ __align__(16) ushort sm[4096];
  int tid = threadIdx.x;
  const float* xb = x + (size_t)b * Cch * Pp;
  ushort* xTb = xT + (size_t)b * Pp * Cch;
#pragma unroll
  for (int it = 0; it < 4; ++it) {
    int cc = tid + it * 256;
    int r = cc >> 4, c4 = cc & 15;
    floatx4 v = *(const floatx4*)&xb[(size_t)(c0 + r) * Pp + p0 + c4 * 4];
    ushortx4 o;
#pragma unroll
    for (int j = 0; j < 4; ++j) o[j] = f2bf(v[j]);
    *(ushortx4*)&sm[swz(r, c4 >> 1) * 8 + (c4 & 1) * 4] = o;
  }
  __syncthreads();
#pragma unroll
  for (int it = 0; it < 2; ++it) {
    int cc = tid + it * 256;
    int pl = cc >> 3, c8 = cc & 7;
    ushortx8 o;
#pragma unroll
    for (int j = 0; j < 8; ++j) {
      int c = c8 * 8 + j;
      o[j] = sm[swz(c, pl >> 3) * 8 + (pl & 7)];
    }
    *(ushortx8*)&xTb[(size_t)(p0 + pl) * Cch + c0 + c8 * 8] = o;
  }
}

// ---------------------------------------------------------------------------
// D_bf16[m][n] = sum_k A[m][k]*W[n][k] + bias[n]  (A,W bf16; bias fp32)
// 128x128 block tile, BK=64, 4 waves each 64x64.
// 2-deep double-buffered pipeline: stage tile t+1 (global_load_lds, width 16,
// pre-swizzled source) while computing tile t; ONE barrier per K-step.
// LDS 64KB: A0@0 B0@8192 A1@16384 B1@24576 (ushort offsets)
// ---------------------------------------------------------------------------
__global__ __launch_bounds__(256) void k_gemm_bt(const ushort* __restrict__ A,
                                                 const ushort* __restrict__ W,
                                                 const float* __restrict__ bias,
                                                 ushort* __restrict__ D,
                                                 int K, int ldD,
                                                 size_t sAb, size_t sDb) {
  __shared__ __align__(16) ushort sm[32768];
  int tid = threadIdx.x;
  int lane = tid & 63, w = tid >> 6;
  int wm = (w & 1) * 64, wn = (w >> 1) * 64;
  size_t m0 = (size_t)blockIdx.y * 128;
  size_t n0 = (size_t)blockIdx.x * 128;
  const ushort* Ab = A + (size_t)blockIdx.z * sAb;
  ushort* Db = D + (size_t)blockIdx.z * sDb;

  // invariant per-lane staging source addrs (kb added per tile)
  const ushort *aS[4], *wS[4];
#pragma unroll
  for (int it = 0; it < 4; ++it) {
    int i = it * 256 + tid;  // chunk 0..1023
    int r = i >> 3;
    int c8 = (i & 7) ^ (r & 7) ^ ((r >> 3) & 7);  // inverse (=same) swizzle
    aS[it] = &Ab[(m0 + r) * (size_t)K + c8 * 8];
    wS[it] = &W[(n0 + r) * (size_t)K + c8 * 8];
  }
  int dof = w * 512;  // wave-uniform LDS chunk base (ushorts)

  floatx4 zero4 = {0.f, 0.f, 0.f, 0.f};
  floatx4 acc[4][4];
#pragma unroll
  for (int i = 0; i < 4; ++i)
#pragma unroll
    for (int j = 0; j < 4; ++j) acc[i][j] = zero4;

  const int NT = K >> 6;
  // prologue: stage tile 0 into buf0
#pragma unroll
  for (int it = 0; it < 4; ++it) {
    gll16(aS[it], &sm[it * 2048 + dof]);
    gll16(wS[it], &sm[8192 + it * 2048 + dof]);
  }
  __syncthreads();

  int cur = 0;
  for (int t = 0; t < NT; ++t) {
    ushort* cA = sm + (cur << 14);
    ushort* cB = cA + 8192;
    if (t + 1 < NT) {
      ushort* nA = sm + ((cur ^ 1) << 14);
      ushort* nB = nA + 8192;
      int kb = (t + 1) << 6;
#pragma unroll
      for (int it = 0; it < 4; ++it) {
        gll16(aS[it] + kb, &nA[it * 2048 + dof]);
        gll16(wS[it] + kb, &nB[it * 2048 + dof]);
      }
    }
#pragma unroll
    for (int kk = 0; kk < 2; ++kk) {
      int g = kk * 4 + (lane >> 4);
      int rr = lane & 15;
      short8 af[4], bf[4];
#pragma unroll
      for (int i = 0; i < 4; ++i) af[i] = *(const short8*)&cA[swz(wm + i * 16 + rr, g) * 8];
#pragma unroll
      for (int j = 0; j < 4; ++j) bf[j] = *(const short8*)&cB[swz(wn + j * 16 + rr, g) * 8];
#pragma unroll
      for (int i = 0; i < 4; ++i)
#pragma unroll
        for (int j = 0; j < 4; ++j)
          acc[i][j] = __builtin_amdgcn_mfma_f32_16x16x32_bf16(af[i], bf[j], acc[i][j], 0, 0, 0);
    }
    __syncthreads();  // drains own vmcnt (staged loads) + lgkm; next tile ready
    cur ^= 1;
  }

  int quad = lane >> 4, col = lane & 15;
#pragma unroll
  for (int j = 0; j < 4; ++j) {
    int n_loc = wn + j * 16 + col;
    float bj = bias[n0 + n_loc];
#pragma unroll
    for (int i = 0; i < 4; ++i)
#pragma unroll
      for (int r = 0; r < 4; ++r) {
        int m_loc = wm + i * 16 + quad * 4 + r;
        sm[(m_loc * 16 + ((n_loc >> 3) ^ (m_loc & 7) ^ ((m_loc >> 3) & 7))) * 8 + (n_loc & 7)] =
            f2bf(acc[i][j][r] + bj);
      }
  }
  __syncthreads();
#pragma unroll
  for (int it = 0; it < 8; ++it) {
    int cc = tid + it * 256;
    int m_loc = cc >> 4, cn = cc & 15;
    uintx4 v = *(const uintx4*)&sm[(m_loc * 16 + (cn ^ (m_loc & 7) ^ ((m_loc >> 3) & 7))) * 8];
    *(uintx4*)&Db[(m0 + m_loc) * (size_t)ldD + n0 + cn * 8] = v;
  }
}

// ---------------------------------------------------------------------------
// GEMM2: D_fp32[n][m] = sum_k A[m][k]*W[n][k] + bias[n]   (transposed fp32 out)
// Same 2-deep pipeline. Fused BN partials: per-block per-channel (sum,sumsq)
// written ONCE to scratch [c][1024] (part = batch*64 + m-block) — no atomics.
// ---------------------------------------------------------------------------
__global__ __launch_bounds__(256) void k_gemm2_t(const ushort* __restrict__ A,
                                                 const ushort* __restrict__ W,
                                                 const float* __restrict__ bias,
                                                 float* __restrict__ D,
                                                 int K, int ldD,
                                                 size_t sAb, size_t sDb, int bBase,
                                                 float* __restrict__ psum,
                                                 float* __restrict__ psq) {
  __shared__ __align__(16) ushort sm[32768];
  float* smf = (float*)sm;
  int tid = threadIdx.x;
  int lane = tid & 63, w = tid >> 6;
  int wm = (w & 1) * 64, wn = (w >> 1) * 64;
  size_t m0 = (size_t)blockIdx.y * 128;
  size_t n0 = (size_t)blockIdx.x * 128;
  const ushort* Ab = A + (size_t)blockIdx.z * sAb;
  float* Db = D + (size_t)blockIdx.z * sDb;
  int part = (bBase + blockIdx.z) * 64 + blockIdx.y;

  const ushort *aS[4], *wS[4];
#pragma unroll
  for (int it = 0; it < 4; ++it) {
    int i = it * 256 + tid;
    int r = i >> 3;
    int c8 = (i & 7) ^ (r & 7) ^ ((r >> 3) & 7);
    aS[it] = &Ab[(m0 + r) * (size_t)K + c8 * 8];
    wS[it] = &W[(n0 + r) * (size_t)K + c8 * 8];
  }
  int dof = w * 512;

  floatx4 zero4 = {0.f, 0.f, 0.f, 0.f};
  floatx4 acc[4][4];
#pragma unroll
  for (int i = 0; i < 4; ++i)
#pragma unroll
    for (int j = 0; j < 4; ++j) acc[i][j] = zero4;

  const int NT = K >> 6;
#pragma unroll
  for (int it = 0; it < 4; ++it) {
    gll16(aS[it], &sm[it * 2048 + dof]);
    gll16(wS[it], &sm[8192 + it * 2048 + dof]);
  }
  __syncthreads();

  int cur = 0;
  for (int t = 0; t < NT; ++t) {
    ushort* cA = sm + (cur << 14);
    ushort* cB = cA + 8192;
    if (t + 1 < NT) {
      ushort* nA = sm + ((cur ^ 1) << 14);
      ushort* nB = nA + 8192;
      int kb = (t + 1) << 6;
#pragma unroll
      for (int it = 0; it < 4; ++it) {
        gll16(aS[it] + kb, &nA[it * 2048 + dof]);
        gll16(wS[it] + kb, &nB[it * 2048 + dof]);
      }
    }
#pragma unroll
    for (int kk = 0; kk < 2; ++kk) {
      int g = kk * 4 + (lane >> 4);
      int rr = lane & 15;
      short8 af[4], bf[4];
#pragma unroll
      for (int i = 0; i < 4; ++i) af[i] = *(const short8*)&cA[swz(wm + i * 16 + rr, g) * 8];
#pragma unroll
      for (int j = 0; j < 4; ++j) bf[j] = *(const short8*)&cB[swz(wn + j * 16 + rr, g) * 8];
#pragma unroll
      for (int i = 0; i < 4; ++i)
#pragma unroll
        for (int j = 0; j < 4; ++j)
          acc[i][j] = __builtin_amdgcn_mfma_f32_16x16x32_bf16(af[i], bf[j], acc[i][j], 0, 0, 0);
    }
    __syncthreads();
    cur ^= 1;
  }

  int quad = lane >> 4, col = lane & 15;
#pragma unroll
  for (int h = 0; h < 2; ++h) {
    __syncthreads();
    if ((w >> 1) == h) {  // waves whose wn == h*64 own this half
#pragma unroll
      for (int j = 0; j < 4; ++j) {
        int n1 = j * 16 + col;  // row within half
        float bj = bias[n0 + h * 64 + n1];
#pragma unroll
        for (int i = 0; i < 4; ++i) {
          int mb = wm + i * 16 + quad * 4;
          floatx4 v4;
#pragma unroll
          for (int r = 0; r < 4; ++r) v4[r] = acc[i][j][r] + bj;
          *(floatx4*)&smf[n1 * 128 + (mb ^ ((n1 & 7) << 2))] = v4;
        }
      }
    }
    __syncthreads();
#pragma unroll
    for (int it = 0; it < 8; ++it) {
      int cc = tid + it * 256;
      int n2 = cc >> 5, ck = cc & 31;
      floatx4 v = *(const floatx4*)&smf[n2 * 128 + ((ck * 4) ^ ((n2 & 7) << 2))];
      *(floatx4*)&Db[(n0 + h * 64 + n2) * (size_t)ldD + m0 + ck * 4] = v;
      // fused BN partials: 32 threads (same n2) reduce 128 m-values
      float s = v[0] + v[1] + v[2] + v[3];
      float q = v[0] * v[0] + v[1] * v[1] + v[2] * v[2] + v[3] * v[3];
#pragma unroll
      for (int off = 16; off > 0; off >>= 1) {
        s += __shfl_down(s, off, 32);
        q += __shfl_down(q, off, 32);
      }
      if ((tid & 31) == 0) {
        size_t c = n0 + h * 64 + n2;
        psum[c * 1024 + part] = s;
        psq[c * 1024 + part] = q;
      }
    }
  }
}

// ---------------------------------------------------------------------------
// attention: block per (h,t), blockIdx.y = batch within group
// qkv bf16 [p][1536]; aT bf16 [p][512]
// ---------------------------------------------------------------------------
__global__ __launch_bounds__(256) void k_attn(const ushort* __restrict__ qkv,
                                              ushort* __restrict__ aT,
                                              size_t sQb, size_t sAb) {
  int bx = blockIdx.x;
  int t = bx & 127, h = bx >> 7;
  __shared__ __align__(16) ushort sm[16384];
  ushort* qs = sm;
  ushort* ks = sm + 4096;
  ushort* vt = sm + 8192;
  ushort* ss = sm + 12288;
  int tid = threadIdx.x, lane = tid & 63, w = tid >> 6;
  int quad = lane >> 4, col = lane & 15;
  const ushort* base = qkv + (size_t)blockIdx.y * sQb + (size_t)(t * 64) * C3 + h * 64;

#pragma unroll
  for (int it = 0; it < 2; ++it) {
    int i = it * 256 + tid;  // chunk 0..511
    int r = i >> 3;
    int c8 = (i & 7) ^ (r & 7) ^ ((r >> 3) & 7);
    gll16(&base[(size_t)r * C3 + c8 * 8], &qs[(size_t)(it * 256 + w * 64) * 8]);
    gll16(&base[(size_t)r * C3 + 512 + c8 * 8], &ks[(size_t)(it * 256 + w * 64) * 8]);
    int n = i >> 3, d8 = i & 7;
    ushortx8 vv = *(const ushortx8*)&base[(size_t)n * C3 + 1024 + d8 * 8];
#pragma unroll
    for (int j = 0; j < 8; ++j) {
      int dp = d8 * 8 + j;
      vt[swz(dp, n >> 3) * 8 + (n & 7)] = vv[j];  // vT[d][m]
    }
  }
  __syncthreads();

  floatx4 zero4 = {0.f, 0.f, 0.f, 0.f};
  floatx4 accs[4] = {zero4, zero4, zero4, zero4};
#pragma unroll
  for (int kk = 0; kk < 2; ++kk) {
    int g = kk * 4 + quad;
    short8 aq = *(const short8*)&qs[swz(w * 16 + col, g) * 8];
#pragma unroll
    for (int j = 0; j < 4; ++j) {
      short8 bk = *(const short8*)&ks[swz(j * 16 + col, g) * 8];
      accs[j] = __builtin_amdgcn_mfma_f32_16x16x32_bf16(aq, bk, accs[j], 0, 0, 0);
    }
  }
#pragma unroll
  for (int j = 0; j < 4; ++j)
#pragma unroll
    for (int r = 0; r < 4; ++r) {
      int n = w * 16 + quad * 4 + r, m = j * 16 + col;
      ss[swz(n, m >> 3) * 8 + (m & 7)] = f2bf(accs[j][r] * 0.125f);
    }
  __syncthreads();

  floatx4 acco[4] = {zero4, zero4, zero4, zero4};
#pragma unroll
  for (int kk = 0; kk < 2; ++kk) {
    int g = kk * 4 + quad;
    short8 as = *(const short8*)&ss[swz(w * 16 + col, g) * 8];
#pragma unroll
    for (int j = 0; j < 4; ++j) {
      short8 bv = *(const short8*)&vt[swz(j * 16 + col, g) * 8];
      acco[j] = __builtin_amdgcn_mfma_f32_16x16x32_bf16(as, bv, acco[j], 0, 0, 0);
    }
  }
#pragma unroll
  for (int j = 0; j < 4; ++j)
#pragma unroll
    for (int r = 0; r < 4; ++r) {
      int n = w * 16 + quad * 4 + r, dp = j * 16 + col;
      qs[swz(n, dp >> 3) * 8 + (dp & 7)] = f2bf(acco[j][r]);  // qs dead, reuse
    }
  __syncthreads();
  ushort* aTb = aT + (size_t)blockIdx.y * sAb + (size_t)(t * 64) * Cch + h * 64;
#pragma unroll
  for (int it = 0; it < 2; ++it) {
    int cc = tid + it * 256;
    int n = cc >> 3, c8 = cc & 7;
    uintx4 v = *(const uintx4*)&qs[swz(n, c8) * 8];
    *(uintx4*)&aTb[(size_t)n * Cch + c8 * 8] = v;
  }
}

// ---------------------------------------------------------------------------
// BN finalize (reduce scratch partials) + in-place BN+residual
// ---------------------------------------------------------------------------
__global__ __launch_bounds__(256) void k_bnfin(const float* __restrict__ psum,
                                               const float* __restrict__ psq,
                                               const float* __restrict__ gamma,
                                               const float* __restrict__ beta,
                                               float* __restrict__ scaleS,
                                               float* __restrict__ shiftS) {
  int c = blockIdx.x;  // 512 blocks, one channel each
  int tid = threadIdx.x;
  floatx4 v = *(const floatx4*)&psum[(size_t)c * 1024 + tid * 4];
  floatx4 u = *(const floatx4*)&psq[(size_t)c * 1024 + tid * 4];
  float s = v[0] + v[1] + v[2] + v[3];
  float q = u[0] + u[1] + u[2] + u[3];
#pragma unroll
  for (int off = 32; off > 0; off >>= 1) {
    s += __shfl_down(s, off);
    q += __shfl_down(q, off);
  }
  __shared__ float rs[4], rq[4];
  if ((tid & 63) == 0) { rs[tid >> 6] = s; rq[tid >> 6] = q; }
  __syncthreads();
  if (tid == 0) {
    float S = rs[0] + rs[1] + rs[2] + rs[3];
    float Q = rq[0] + rq[1] + rq[2] + rq[3];
    float inv = 1.0f / (float)BPOS;
    float mean = S * inv;
    float var = Q * inv - mean * mean;
    float sc = gamma[c] * rsqrtf(var + 1e-5f);
    scaleS[c] = sc;
    shiftS[c] = beta[c] - mean * sc;
  }
}

// y (= d_out fp32, channel-major) in place: y = y*scale[c] + shift[c] + x
__global__ __launch_bounds__(256) void k_final(const float* __restrict__ x,
                                               float* __restrict__ y,
                                               const float* __restrict__ scaleS,
                                               const float* __restrict__ shiftS) {
  size_t gid = (size_t)blockIdx.x * 256 + threadIdx.x;
  size_t i4 = gid * 4;
  int c = (int)((i4 >> 13) & 511);
  float sc = scaleS[c], sh = shiftS[c];
  floatx4 yv = *(floatx4*)&y[i4];
  floatx4 xv = *(const floatx4*)&x[i4];
  floatx4 o;
#pragma unroll
  for (int j = 0; j < 4; ++j) o[j] = yv[j] * sc + sh + xv[j];
  *(floatx4*)&y[i4] = o;
}

// ---------------------------------------------------------------------------
extern "C" void kernel_launch(void* const* d_in, const int* in_sizes, int n_in,
                              void* d_out, int out_size, void* d_ws, size_t ws_size,
                              hipStream_t stream) {
  const float* x      = (const float*)d_in[0];
  const float* w_qkv  = (const float*)d_in[1];
  const float* b_qkv  = (const float*)d_in[2];
  const float* w_proj = (const float*)d_in[3];
  const float* b_proj = (const float*)d_in[4];
  const float* gamma  = (const float*)d_in[5];
  const float* beta   = (const float*)d_in[6];
  float* outf = (float*)d_out;  // 268,435,456 B

  // ws (~36 MB): qkv_ws (batch 15) | aT_ws (batch 15) | wqkvb | wprojb | stats
  // BN partial scratch (4 MB) ALIASES qkv_ws: batch-15 qkv is fully consumed
  // by k_attn before any k_gemm2_t (stream-ordered), so the region is dead.
  char* ws = (char*)d_ws;
  ushort* qkv_ws = (ushort*)ws;                         // 25,165,824 B
  float*  psum   = (float*)ws;                          //  2,097,152 B (alias)
  float*  psq    = (float*)(ws + 2097152ull);           //  2,097,152 B (alias)
  ushort* aT_ws  = (ushort*)(ws + 25165824ull);         //  8,388,608 B
  ushort* wqkvb  = (ushort*)(ws + 33554432ull);         //  1,572,864 B
  ushort* wprojb = (ushort*)(ws + 35127296ull);         //    524,288 B
  float*  st     = (float*)(ws + 35651584ull);          //      8 KB
  float* scaleS = st, *shiftS = st + 512;

  // d_out aliasing plan (byte-exact, verified offsets):
  //  - xT bf16 [16][8192][512] lives in the UPPER half [134217728, 268435456).
  //    Slab b: [134217728 + b*8388608, +8388608). Dead after gemm1(b).
  //  - attn writes aT_b OVER its own xT slab (gemm1(b) already consumed it).
  //  - qkv for 5 batches at a time staged in the LOWER half [0, 125829120)
  //    (y not written until all gemm1/attn done).
  //  - gemm2 groups {0-7},{8-11},{12-13},{14}: y-slab stride (16777216 B) is
  //    2x aT stride, so each group's y-writes cover only ALREADY-CONSUMED aT
  //    slabs; boundaries are exact (e.g. y[8..11] ends at 201326592 = aT8
  //    start). Batch 15 would self-overlap, so it routes through ws.
  ushort* xT   = (ushort*)((char*)d_out + 134217728ull);
  ushort* qkvL = (ushort*)d_out;

  const size_t PC = (size_t)Pp * Cch;  // xT / aT batch stride (elements)
  const size_t PQ = (size_t)Pp * C3;   // qkv batch stride (elements)
  const size_t CP = (size_t)Cch * Pp;  // y batch stride (floats)

  k_cvt<<<dim3(384), 256, 0, stream>>>(w_qkv, wqkvb, 3 * Cch * Cch);
  k_cvt<<<dim3(128), 256, 0, stream>>>(w_proj, wprojb, Cch * Cch);
  k_transpose_x<<<dim3(Pp / 64, Cch / 64, Bsz), 256, 0, stream>>>(x, xT);

  // batches 0..14 in groups of 5 (qkv staged in d_out lower half)
  for (int g = 0; g < 3; ++g) {
    int b0 = g * 5;
    k_gemm_bt<<<dim3(C3 / 128, Pp / 128, 5), 256, 0, stream>>>(
        xT + (size_t)b0 * PC, wqkvb, b_qkv, qkvL, Cch, C3, PC, PQ);
    k_attn<<<dim3(Hh * Tt, 5), 256, 0, stream>>>(qkvL, xT + (size_t)b0 * PC, PQ, PC);
  }
  // batch 15 through ws buffers
  k_gemm_bt<<<dim3(C3 / 128, Pp / 128, 1), 256, 0, stream>>>(
      xT + 15 * PC, wqkvb, b_qkv, qkv_ws, Cch, C3, 0, 0);
  k_attn<<<dim3(Hh * Tt, 1), 256, 0, stream>>>(qkv_ws, aT_ws, 0, 0);

  // gemm2 groups (fused BN partials, no atomics)
  k_gemm2_t<<<dim3(Cch / 128, Pp / 128, 8), 256, 0, stream>>>(
      xT + 0 * PC, wprojb, b_proj, outf + 0 * CP, Cch, Pp, PC, CP, 0, psum, psq);
  k_gemm2_t<<<dim3(Cch / 128, Pp / 128, 4), 256, 0, stream>>>(
      xT + 8 * PC, wprojb, b_proj, outf + 8 * CP, Cch, Pp, PC, CP, 8, psum, psq);
  k_gemm2_t<<<dim3(Cch / 128, Pp / 128, 2), 256, 0, stream>>>(
      xT + 12 * PC, wprojb, b_proj, outf + 12 * CP, Cch, Pp, PC, CP, 12, psum, psq);
  k_gemm2_t<<<dim3(Cch / 128, Pp / 128, 1), 256, 0, stream>>>(
      xT + 14 * PC, wprojb, b_proj, outf + 14 * CP, Cch, Pp, 0, 0, 14, psum, psq);
  k_gemm2_t<<<dim3(Cch / 128, Pp / 128, 1), 256, 0, stream>>>(
      aT_ws, wprojb, b_proj, outf + 15 * CP, Cch, Pp, 0, 0, 15, psum, psq);

  k_bnfin<<<dim3(Cch), 256, 0, stream>>>(psum, psq, gamma, beta, scaleS, shiftS);
  k_final<<<dim3(BPOS * Cch / 4 / 256), 256, 0, stream>>>(x, outf, scaleS, shiftS);
}

// Round 3
// 1157.325 us; speedup vs baseline: 1.3099x; 1.0380x over previous
//
#include <hip/hip_runtime.h>

typedef unsigned int uint;
typedef unsigned short ushort;
typedef short short8 __attribute__((ext_vector_type(8)));
typedef float floatx4 __attribute__((ext_vector_type(4)));
typedef ushort ushortx8 __attribute__((ext_vector_type(8)));
typedef ushort ushortx4 __attribute__((ext_vector_type(4)));
typedef uint uintx4 __attribute__((ext_vector_type(4)));

#define DEV static __device__ __forceinline__

#define Bsz 16
#define Cch 512
#define Tt 128
#define Nn 64
#define Hh 8
#define HD 64
#define Pp 8192        /* T*N */
#define BPOS 131072    /* B*P  */
#define C3 1536

// chunk swizzle: tiles stored as 16-byte chunks (8 bf16); row has 8 chunks
DEV int swz(int row, int c8) { return row * 8 + (c8 ^ (row & 7) ^ ((row >> 3) & 7)); }

DEV ushort f2bf(float f) {
  uint u = __float_as_uint(f);
  return (ushort)((u + 0x7FFFu + ((u >> 16) & 1u)) >> 16);  // RNE
}
DEV float bf2f(ushort h) { return __uint_as_float(((uint)h) << 16); }

// async global->LDS, 16B per lane. dst must be wave-uniform base; HW writes
// lane L at dst + L*16. Source address is per-lane (carries the inverse swizzle).
DEV void gll16(const ushort* src, ushort* dst) {
  __builtin_amdgcn_global_load_lds(
      (const __attribute__((address_space(1))) unsigned int*)src,
      (__attribute__((address_space(3))) unsigned int*)dst, 16, 0, 0);
}

// ---------------------------------------------------------------------------
// elementwise fp32 -> bf16 (weights)
// ---------------------------------------------------------------------------
__global__ __launch_bounds__(256) void k_cvt(const float* __restrict__ src,
                                             ushort* __restrict__ dst, int n) {
  int gid = blockIdx.x * 256 + threadIdx.x;
  int i8 = gid * 8;
  if (i8 < n) {
    floatx4 a = *(const floatx4*)&src[i8];
    floatx4 b = *(const floatx4*)&src[i8 + 4];
    ushortx8 o;
#pragma unroll
    for (int j = 0; j < 4; ++j) { o[j] = f2bf(a[j]); o[j + 4] = f2bf(b[j]); }
    *(ushortx8*)&dst[i8] = o;
  }
}

// ---------------------------------------------------------------------------
// x fp32 [b][c][p] -> xT bf16 [b][p][c]  (64x64 tiles via swizzled LDS)
// ---------------------------------------------------------------------------
__global__ __launch_bounds__(256) void k_transpose_x(const float* __restrict__ x,
                                                     ushort* __restrict__ xT) {
  int p0 = blockIdx.x * 64, c0 = blockIdx.y * 64, b = blockIdx.z;
  __shared__ __align__(16) ushort sm[4096];
  int tid = threadIdx.x;
  const float* xb = x + (size_t)b * Cch * Pp;
  ushort* xTb = xT + (size_t)b * Pp * Cch;
#pragma unroll
  for (int it = 0; it < 4; ++it) {
    int cc = tid + it * 256;
    int r = cc >> 4, c4 = cc & 15;
    floatx4 v = *(const floatx4*)&xb[(size_t)(c0 + r) * Pp + p0 + c4 * 4];
    ushortx4 o;
#pragma unroll
    for (int j = 0; j < 4; ++j) o[j] = f2bf(v[j]);
    *(ushortx4*)&sm[swz(r, c4 >> 1) * 8 + (c4 & 1) * 4] = o;
  }
  __syncthreads();
#pragma unroll
  for (int it = 0; it < 2; ++it) {
    int cc = tid + it * 256;
    int pl = cc >> 3, c8 = cc & 7;
    ushortx8 o;
#pragma unroll
    for (int j = 0; j < 8; ++j) {
      int c = c8 * 8 + j;
      o[j] = sm[swz(c, pl >> 3) * 8 + (pl & 7)];
    }
    *(ushortx8*)&xTb[(size_t)(p0 + pl) * Cch + c0 + c8 * 8] = o;
  }
}

// ---------------------------------------------------------------------------
// D_bf16[m][n] = sum_k A[m][k]*W[n][k] + bias[n]  (A,W bf16; bias fp32)
// 128x128 block tile, BK=64, 4 waves each 64x64.
// 2-deep double-buffered pipeline: stage tile t+1 (global_load_lds, width 16,
// pre-swizzled source) while computing tile t; ONE barrier per K-step.
// LDS 64KB: A0@0 B0@8192 A1@16384 B1@24576 (ushort offsets)
// ---------------------------------------------------------------------------
__global__ __launch_bounds__(256) void k_gemm_bt(const ushort* __restrict__ A,
                                                 const ushort* __restrict__ W,
                                                 const float* __restrict__ bias,
                                                 ushort* __restrict__ D,
                                                 int K, int ldD,
                                                 size_t sAb, size_t sDb) {
  __shared__ __align__(16) ushort sm[32768];
  int tid = threadIdx.x;
  int lane = tid & 63, w = tid >> 6;
  int wm = (w & 1) * 64, wn = (w >> 1) * 64;
  size_t m0 = (size_t)blockIdx.y * 128;
  size_t n0 = (size_t)blockIdx.x * 128;
  const ushort* Ab = A + (size_t)blockIdx.z * sAb;
  ushort* Db = D + (size_t)blockIdx.z * sDb;

  // invariant per-lane staging source addrs (kb added per tile)
  const ushort *aS[4], *wS[4];
#pragma unroll
  for (int it = 0; it < 4; ++it) {
    int i = it * 256 + tid;  // chunk 0..1023
    int r = i >> 3;
    int c8 = (i & 7) ^ (r & 7) ^ ((r >> 3) & 7);  // inverse (=same) swizzle
    aS[it] = &Ab[(m0 + r) * (size_t)K + c8 * 8];
    wS[it] = &W[(n0 + r) * (size_t)K + c8 * 8];
  }
  int dof = w * 512;  // wave-uniform LDS chunk base (ushorts)

  floatx4 zero4 = {0.f, 0.f, 0.f, 0.f};
  floatx4 acc[4][4];
#pragma unroll
  for (int i = 0; i < 4; ++i)
#pragma unroll
    for (int j = 0; j < 4; ++j) acc[i][j] = zero4;

  const int NT = K >> 6;
  // prologue: stage tile 0 into buf0
#pragma unroll
  for (int it = 0; it < 4; ++it) {
    gll16(aS[it], &sm[it * 2048 + dof]);
    gll16(wS[it], &sm[8192 + it * 2048 + dof]);
  }
  __syncthreads();

  int cur = 0;
  for (int t = 0; t < NT; ++t) {
    ushort* cA = sm + (cur << 14);
    ushort* cB = cA + 8192;
    if (t + 1 < NT) {
      ushort* nA = sm + ((cur ^ 1) << 14);
      ushort* nB = nA + 8192;
      int kb = (t + 1) << 6;
#pragma unroll
      for (int it = 0; it < 4; ++it) {
        gll16(aS[it] + kb, &nA[it * 2048 + dof]);
        gll16(wS[it] + kb, &nB[it * 2048 + dof]);
      }
    }
#pragma unroll
    for (int kk = 0; kk < 2; ++kk) {
      int g = kk * 4 + (lane >> 4);
      int rr = lane & 15;
      short8 af[4], bf[4];
#pragma unroll
      for (int i = 0; i < 4; ++i) af[i] = *(const short8*)&cA[swz(wm + i * 16 + rr, g) * 8];
#pragma unroll
      for (int j = 0; j < 4; ++j) bf[j] = *(const short8*)&cB[swz(wn + j * 16 + rr, g) * 8];
#pragma unroll
      for (int i = 0; i < 4; ++i)
#pragma unroll
        for (int j = 0; j < 4; ++j)
          acc[i][j] = __builtin_amdgcn_mfma_f32_16x16x32_bf16(af[i], bf[j], acc[i][j], 0, 0, 0);
    }
    __syncthreads();  // drains own vmcnt (staged loads) + lgkm; next tile ready
    cur ^= 1;
  }

  int quad = lane >> 4, col = lane & 15;
#pragma unroll
  for (int j = 0; j < 4; ++j) {
    int n_loc = wn + j * 16 + col;
    float bj = bias[n0 + n_loc];
#pragma unroll
    for (int i = 0; i < 4; ++i)
#pragma unroll
      for (int r = 0; r < 4; ++r) {
        int m_loc = wm + i * 16 + quad * 4 + r;
        sm[(m_loc * 16 + ((n_loc >> 3) ^ (m_loc & 7) ^ ((m_loc >> 3) & 7))) * 8 + (n_loc & 7)] =
            f2bf(acc[i][j][r] + bj);
      }
  }
  __syncthreads();
#pragma unroll
  for (int it = 0; it < 8; ++it) {
    int cc = tid + it * 256;
    int m_loc = cc >> 4, cn = cc & 15;
    uintx4 v = *(const uintx4*)&sm[(m_loc * 16 + (cn ^ (m_loc & 7) ^ ((m_loc >> 3) & 7))) * 8];
    *(uintx4*)&Db[(m0 + m_loc) * (size_t)ldD + n0 + cn * 8] = v;
  }
}

// ---------------------------------------------------------------------------
// GEMM2: y_bf16[n][m] = sum_k A[m][k]*W[n][k] + bias[n]   (transposed out)
// Same 2-deep pipeline. Epilogue: fp32 tile -> LDS -> bf16 store (coalesced);
// BN partials computed from the STORED bf16 values (consistent with k_final),
// written once per (channel, part) to scratch [c][1024] — no atomics.
// Single launch z=16; batch 0's y routes to ws (alive during k_final tail).
// ---------------------------------------------------------------------------
__global__ __launch_bounds__(256) void k_gemm2_t(const ushort* __restrict__ A,
                                                 const ushort* __restrict__ W,
                                                 const float* __restrict__ bias,
                                                 ushort* __restrict__ yL,
                                                 ushort* __restrict__ y0,
                                                 int K, int ldD,
                                                 size_t sAb, size_t sDb,
                                                 float* __restrict__ psum,
                                                 float* __restrict__ psq) {
  __shared__ __align__(16) ushort sm[32768];
  float* smf = (float*)sm;
  int tid = threadIdx.x;
  int lane = tid & 63, w = tid >> 6;
  int wm = (w & 1) * 64, wn = (w >> 1) * 64;
  size_t m0 = (size_t)blockIdx.y * 128;
  size_t n0 = (size_t)blockIdx.x * 128;
  const ushort* Ab = A + (size_t)blockIdx.z * sAb;
  ushort* Db = (blockIdx.z == 0) ? y0 : yL + (size_t)blockIdx.z * sDb;
  int part = blockIdx.z * 64 + blockIdx.y;

  const ushort *aS[4], *wS[4];
#pragma unroll
  for (int it = 0; it < 4; ++it) {
    int i = it * 256 + tid;
    int r = i >> 3;
    int c8 = (i & 7) ^ (r & 7) ^ ((r >> 3) & 7);
    aS[it] = &Ab[(m0 + r) * (size_t)K + c8 * 8];
    wS[it] = &W[(n0 + r) * (size_t)K + c8 * 8];
  }
  int dof = w * 512;

  floatx4 zero4 = {0.f, 0.f, 0.f, 0.f};
  floatx4 acc[4][4];
#pragma unroll
  for (int i = 0; i < 4; ++i)
#pragma unroll
    for (int j = 0; j < 4; ++j) acc[i][j] = zero4;

  const int NT = K >> 6;
#pragma unroll
  for (int it = 0; it < 4; ++it) {
    gll16(aS[it], &sm[it * 2048 + dof]);
    gll16(wS[it], &sm[8192 + it * 2048 + dof]);
  }
  __syncthreads();

  int cur = 0;
  for (int t = 0; t < NT; ++t) {
    ushort* cA = sm + (cur << 14);
    ushort* cB = cA + 8192;
    if (t + 1 < NT) {
      ushort* nA = sm + ((cur ^ 1) << 14);
      ushort* nB = nA + 8192;
      int kb = (t + 1) << 6;
#pragma unroll
      for (int it = 0; it < 4; ++it) {
        gll16(aS[it] + kb, &nA[it * 2048 + dof]);
        gll16(wS[it] + kb, &nB[it * 2048 + dof]);
      }
    }
#pragma unroll
    for (int kk = 0; kk < 2; ++kk) {
      int g = kk * 4 + (lane >> 4);
      int rr = lane & 15;
      short8 af[4], bf[4];
#pragma unroll
      for (int i = 0; i < 4; ++i) af[i] = *(const short8*)&cA[swz(wm + i * 16 + rr, g) * 8];
#pragma unroll
      for (int j = 0; j < 4; ++j) bf[j] = *(const short8*)&cB[swz(wn + j * 16 + rr, g) * 8];
#pragma unroll
      for (int i = 0; i < 4; ++i)
#pragma unroll
        for (int j = 0; j < 4; ++j)
          acc[i][j] = __builtin_amdgcn_mfma_f32_16x16x32_bf16(af[i], bf[j], acc[i][j], 0, 0, 0);
    }
    __syncthreads();
    cur ^= 1;
  }

  int quad = lane >> 4, col = lane & 15;
#pragma unroll
  for (int h = 0; h < 2; ++h) {
    __syncthreads();
    if ((w >> 1) == h) {  // waves whose wn == h*64 own this half
#pragma unroll
      for (int j = 0; j < 4; ++j) {
        int n1 = j * 16 + col;  // row within half
        float bj = bias[n0 + h * 64 + n1];
#pragma unroll
        for (int i = 0; i < 4; ++i) {
          int mb = wm + i * 16 + quad * 4;
          floatx4 v4;
#pragma unroll
          for (int r = 0; r < 4; ++r) v4[r] = acc[i][j][r] + bj;
          *(floatx4*)&smf[n1 * 128 + (mb ^ ((n1 & 7) << 2))] = v4;
        }
      }
    }
    __syncthreads();
#pragma unroll
    for (int it = 0; it < 8; ++it) {
      int cc = tid + it * 256;
      int n2 = cc >> 5, ck = cc & 31;
      floatx4 v = *(const floatx4*)&smf[n2 * 128 + ((ck * 4) ^ ((n2 & 7) << 2))];
      ushortx4 o;
#pragma unroll
      for (int r = 0; r < 4; ++r) o[r] = f2bf(v[r]);
      *(ushortx4*)&Db[(n0 + h * 64 + n2) * (size_t)ldD + m0 + ck * 4] = o;
      // BN partials from the STORED bf16 values (exactly what k_final reads)
      float s = 0.f, q = 0.f;
#pragma unroll
      for (int r = 0; r < 4; ++r) {
        float f = bf2f(o[r]);
        s += f;
        q += f * f;
      }
#pragma unroll
      for (int off = 16; off > 0; off >>= 1) {
        s += __shfl_down(s, off, 32);
        q += __shfl_down(q, off, 32);
      }
      if ((tid & 31) == 0) {
        size_t c = n0 + h * 64 + n2;
        psum[c * 1024 + part] = s;
        psq[c * 1024 + part] = q;
      }
    }
  }
}

// ---------------------------------------------------------------------------
// attention: block per (h,t), blockIdx.y = batch within group
// qkv bf16 [p][1536]; aT bf16 [p][512]
// ---------------------------------------------------------------------------
__global__ __launch_bounds__(256) void k_attn(const ushort* __restrict__ qkv,
                                              ushort* __restrict__ aT,
                                              size_t sQb, size_t sAb) {
  int bx = blockIdx.x;
  int t = bx & 127, h = bx >> 7;
  __shared__ __align__(16) ushort sm[16384];
  ushort* qs = sm;
  ushort* ks = sm + 4096;
  ushort* vt = sm + 8192;
  ushort* ss = sm + 12288;
  int tid = threadIdx.x, lane = tid & 63, w = tid >> 6;
  int quad = lane >> 4, col = lane & 15;
  const ushort* base = qkv + (size_t)blockIdx.y * sQb + (size_t)(t * 64) * C3 + h * 64;

#pragma unroll
  for (int it = 0; it < 2; ++it) {
    int i = it * 256 + tid;  // chunk 0..511
    int r = i >> 3;
    int c8 = (i & 7) ^ (r & 7) ^ ((r >> 3) & 7);
    gll16(&base[(size_t)r * C3 + c8 * 8], &qs[(size_t)(it * 256 + w * 64) * 8]);
    gll16(&base[(size_t)r * C3 + 512 + c8 * 8], &ks[(size_t)(it * 256 + w * 64) * 8]);
    int n = i >> 3, d8 = i & 7;
    ushortx8 vv = *(const ushortx8*)&base[(size_t)n * C3 + 1024 + d8 * 8];
#pragma unroll
    for (int j = 0; j < 8; ++j) {
      int dp = d8 * 8 + j;
      vt[swz(dp, n >> 3) * 8 + (n & 7)] = vv[j];  // vT[d][m]
    }
  }
  __syncthreads();

  floatx4 zero4 = {0.f, 0.f, 0.f, 0.f};
  floatx4 accs[4] = {zero4, zero4, zero4, zero4};
#pragma unroll
  for (int kk = 0; kk < 2; ++kk) {
    int g = kk * 4 + quad;
    short8 aq = *(const short8*)&qs[swz(w * 16 + col, g) * 8];
#pragma unroll
    for (int j = 0; j < 4; ++j) {
      short8 bk = *(const short8*)&ks[swz(j * 16 + col, g) * 8];
      accs[j] = __builtin_amdgcn_mfma_f32_16x16x32_bf16(aq, bk, accs[j], 0, 0, 0);
    }
  }
#pragma unroll
  for (int j = 0; j < 4; ++j)
#pragma unroll
    for (int r = 0; r < 4; ++r) {
      int n = w * 16 + quad * 4 + r, m = j * 16 + col;
      ss[swz(n, m >> 3) * 8 + (m & 7)] = f2bf(accs[j][r] * 0.125f);
    }
  __syncthreads();

  floatx4 acco[4] = {zero4, zero4, zero4, zero4};
#pragma unroll
  for (int kk = 0; kk < 2; ++kk) {
    int g = kk * 4 + quad;
    short8 as = *(const short8*)&ss[swz(w * 16 + col, g) * 8];
#pragma unroll
    for (int j = 0; j < 4; ++j) {
      short8 bv = *(const short8*)&vt[swz(j * 16 + col, g) * 8];
      acco[j] = __builtin_amdgcn_mfma_f32_16x16x32_bf16(as, bv, acco[j], 0, 0, 0);
    }
  }
#pragma unroll
  for (int j = 0; j < 4; ++j)
#pragma unroll
    for (int r = 0; r < 4; ++r) {
      int n = w * 16 + quad * 4 + r, dp = j * 16 + col;
      qs[swz(n, dp >> 3) * 8 + (dp & 7)] = f2bf(acco[j][r]);  // qs dead, reuse
    }
  __syncthreads();
  ushort* aTb = aT + (size_t)blockIdx.y * sAb + (size_t)(t * 64) * Cch + h * 64;
#pragma unroll
  for (int it = 0; it < 2; ++it) {
    int cc = tid + it * 256;
    int n = cc >> 3, c8 = cc & 7;
    uintx4 v = *(const uintx4*)&qs[swz(n, c8) * 8];
    *(uintx4*)&aTb[(size_t)n * Cch + c8 * 8] = v;
  }
}

// ---------------------------------------------------------------------------
// BN finalize (reduce scratch partials)
// ---------------------------------------------------------------------------
__global__ __launch_bounds__(256) void k_bnfin(const float* __restrict__ psum,
                                               const float* __restrict__ psq,
                                               const float* __restrict__ gamma,
                                               const float* __restrict__ beta,
                                               float* __restrict__ scaleS,
                                               float* __restrict__ shiftS) {
  int c = blockIdx.x;  // 512 blocks, one channel each
  int tid = threadIdx.x;
  floatx4 v = *(const floatx4*)&psum[(size_t)c * 1024 + tid * 4];
  floatx4 u = *(const floatx4*)&psq[(size_t)c * 1024 + tid * 4];
  float s = v[0] + v[1] + v[2] + v[3];
  float q = u[0] + u[1] + u[2] + u[3];
#pragma unroll
  for (int off = 32; off > 0; off >>= 1) {
    s += __shfl_down(s, off);
    q += __shfl_down(q, off);
  }
  __shared__ float rs[4], rq[4];
  if ((tid & 63) == 0) { rs[tid >> 6] = s; rq[tid >> 6] = q; }
  __syncthreads();
  if (tid == 0) {
    float S = rs[0] + rs[1] + rs[2] + rs[3];
    float Q = rq[0] + rq[1] + rq[2] + rq[3];
    float inv = 1.0f / (float)BPOS;
    float mean = S * inv;
    float var = Q * inv - mean * mean;
    float sc = gamma[c] * rsqrtf(var + 1e-5f);
    scaleS[c] = sc;
    shiftS[c] = beta[c] - mean * sc;
  }
}

// out[b][c][p] = y_bf16[b][c][p]*scale[c] + shift[c] + x[b][c][p]
// y, x, out bases point at the GROUP start; layouts are linearly congruent.
__global__ __launch_bounds__(256) void k_final(const float* __restrict__ x,
                                               const ushort* __restrict__ y,
                                               float* __restrict__ out,
                                               const float* __restrict__ scaleS,
                                               const float* __restrict__ shiftS) {
  size_t gid = (size_t)blockIdx.x * 256 + threadIdx.x;
  size_t i8 = gid * 8;
  int c = (int)((i8 >> 13) & 511);
  float sc = scaleS[c], sh = shiftS[c];
  ushortx8 yv = *(const ushortx8*)&y[i8];
  floatx4 x0 = *(const floatx4*)&x[i8];
  floatx4 x1 = *(const floatx4*)&x[i8 + 4];
  floatx4 o0, o1;
#pragma unroll
  for (int j = 0; j < 4; ++j) {
    o0[j] = bf2f(yv[j]) * sc + sh + x0[j];
    o1[j] = bf2f(yv[j + 4]) * sc + sh + x1[j];
  }
  *(floatx4*)&out[i8] = o0;
  *(floatx4*)&out[i8 + 4] = o1;
}

// ---------------------------------------------------------------------------
extern "C" void kernel_launch(void* const* d_in, const int* in_sizes, int n_in,
                              void* d_out, int out_size, void* d_ws, size_t ws_size,
                              hipStream_t stream) {
  const float* x      = (const float*)d_in[0];
  const float* w_qkv  = (const float*)d_in[1];
  const float* b_qkv  = (const float*)d_in[2];
  const float* w_proj = (const float*)d_in[3];
  const float* b_proj = (const float*)d_in[4];
  const float* gamma  = (const float*)d_in[5];
  const float* beta   = (const float*)d_in[6];
  float* outf = (float*)d_out;  // 268,435,456 B

  // ws layout: psum 2M | psq 2M | y0 8.39M | ... | wqkvb | wprojb | st
  char* ws = (char*)d_ws;
  float*  psum   = (float*)ws;                          // 2,097,152 B
  float*  psq    = (float*)(ws + 2097152ull);           // 2,097,152 B
  ushort* y0ws   = (ushort*)(ws + 4194304ull);          // 8,388,608 B
  ushort* wqkvb  = (ushort*)(ws + 33554432ull);         // 1,572,864 B
  ushort* wprojb = (ushort*)(ws + 35127296ull);         //   524,288 B
  float*  st     = (float*)(ws + 35651584ull);          //     8 KB
  float* scaleS = st, *shiftS = st + 512;

  // d_out aliasing plan (byte-exact):
  //  Phase A (gemm1/attn): xT slabs b in UPPER half [134.2M + b*8.39M); attn
  //    writes aT_b over its own xT slab. qkv for <=5 batches staged in LOWER
  //    half [0, 126M). Batch 15 reuses qkvL slot 0.
  //  Phase B (gemm2 z=16): reads aT (upper), writes y bf16 slabs 1..15 in
  //    LOWER half [8.39M, 134.2M) (qkv staging dead); y0 -> ws.
  //  Phase C (k_final, reverse groups): {8-15} writes [134.2M,268.4M) (aT
  //    dead), reads y[67.1M,134.2M); {4-7} writes [67.1,134.2M) reads
  //    [33.6,67.1M); {2-3} writes [33.6,67.1M) reads [16.8,33.6M); {1}
  //    writes [16.8,33.6M) reads [8.39,16.8M); {0} writes [0,16.8M) reads
  //    y0 from ws. Every group's write region only covers y-slabs already
  //    consumed by earlier groups.
  ushort* xT   = (ushort*)((char*)d_out + 134217728ull);
  ushort* qkvL = (ushort*)d_out;
  ushort* yL   = (ushort*)d_out;  // y slab b at yL + b*PC (b>=1)

  const size_t PC = (size_t)Pp * Cch;  // xT / aT / y batch stride (elements)
  const size_t PQ = (size_t)Pp * C3;   // qkv batch stride (elements)
  const size_t CP = (size_t)Cch * Pp;  // out batch stride (floats)

  k_cvt<<<dim3(384), 256, 0, stream>>>(w_qkv, wqkvb, 3 * Cch * Cch);
  k_cvt<<<dim3(128), 256, 0, stream>>>(w_proj, wprojb, Cch * Cch);
  k_transpose_x<<<dim3(Pp / 64, Cch / 64, Bsz), 256, 0, stream>>>(x, xT);

  // batches 0..14 in groups of 5 (qkv staged in d_out lower half)
  for (int g = 0; g < 3; ++g) {
    int b0 = g * 5;
    k_gemm_bt<<<dim3(C3 / 128, Pp / 128, 5), 256, 0, stream>>>(
        xT + (size_t)b0 * PC, wqkvb, b_qkv, qkvL, Cch, C3, PC, PQ);
    k_attn<<<dim3(Hh * Tt, 5), 256, 0, stream>>>(qkvL, xT + (size_t)b0 * PC, PQ, PC);
  }
  // batch 15 through qkvL slot 0; aT15 over xT15 like the others
  k_gemm_bt<<<dim3(C3 / 128, Pp / 128, 1), 256, 0, stream>>>(
      xT + 15 * PC, wqkvb, b_qkv, qkvL, Cch, C3, 0, 0);
  k_attn<<<dim3(Hh * Tt, 1), 256, 0, stream>>>(qkvL, xT + 15 * PC, 0, 0);

  // gemm2: ONE launch, all 16 batches (fused BN partials from stored bf16 y)
  k_gemm2_t<<<dim3(Cch / 128, Pp / 128, 16), 256, 0, stream>>>(
      xT, wprojb, b_proj, yL, y0ws, Cch, Pp, PC, PC, psum, psq);

  k_bnfin<<<dim3(Cch), 256, 0, stream>>>(psum, psq, gamma, beta, scaleS, shiftS);

  // k_final reverse-ordered groups (see aliasing plan)
  k_final<<<dim3(8 * 2048), 256, 0, stream>>>(x + 8 * CP, yL + 8 * PC, outf + 8 * CP, scaleS, shiftS);
  k_final<<<dim3(4 * 2048), 256, 0, stream>>>(x + 4 * CP, yL + 4 * PC, outf + 4 * CP, scaleS, shiftS);
  k_final<<<dim3(2 * 2048), 256, 0, stream>>>(x + 2 * CP, yL + 2 * PC, outf + 2 * CP, scaleS, shiftS);
  k_final<<<dim3(1 * 2048), 256, 0, stream>>>(x + 1 * CP, yL + 1 * PC, outf + 1 * CP, scaleS, shiftS);
  k_final<<<dim3(1 * 2048), 256, 0, stream>>>(x, y0ws, outf, scaleS, shiftS);
}